// Round 6
// baseline (710.827 us; speedup 1.0000x reference)
//
#include <hip/hip_runtime.h>
#include <hip/hip_bf16.h>
#include <cstdint>

#define BB 32
#define NN 577
#define CC 768
#define HH 12
#define HIDN 3072
#define MROWS (BB*NN)   // 18464

typedef __attribute__((ext_vector_type(8))) short bf16x8;   // 8 bf16 = 4 VGPRs
typedef __attribute__((ext_vector_type(4))) float f32x4;

__device__ __forceinline__ float b2f(unsigned short u) {
    union { float f; unsigned int i; } x; x.i = ((unsigned int)u) << 16; return x.f;
}
__device__ __forceinline__ unsigned short f2b(float f) {
    union { float f; unsigned int i; } x; x.f = f;
    unsigned int i = x.i;
    i += 0x7fffu + ((i >> 16) & 1u);   // round-to-nearest-even
    return (unsigned short)(i >> 16);
}

__device__ __forceinline__ void async16(const void* g, void* l) {
    __builtin_amdgcn_global_load_lds(
        (const __attribute__((address_space(1))) uint32_t*)g,
        (__attribute__((address_space(3))) uint32_t*)l, 16, 0, 0);
}

// Fast exact-GELU: erf via Abramowitz-Stegun 7.1.26 (|err|<=1.5e-7),
// rcp + exp are single HW instrs. ~13 VALU vs ~45 for libm erff.
__device__ __forceinline__ float gelu_f(float v) {
    float ax = fabsf(v) * 0.70710678118654752f;
    float t = __builtin_amdgcn_rcpf(1.0f + 0.3275911f * ax);
    float poly = t * (0.254829592f + t * (-0.284496736f + t * (1.421413741f +
                 t * (-1.453152027f + t * 1.061405429f))));
    float e = __expf(-ax * ax);
    float erf_abs = 1.0f - poly * e;
    float erf_v = (v >= 0.f) ? erf_abs : -erf_abs;
    return 0.5f * v * (1.0f + erf_v);
}

// ---------------------------------------------------------------------------
// fp32 -> bf16 weight conversion (4 matrices in one kernel)
// ---------------------------------------------------------------------------
__global__ void cvt4(const float* __restrict__ a, int na, unsigned short* __restrict__ oa,
                     const float* __restrict__ b, int nb, unsigned short* __restrict__ ob,
                     const float* __restrict__ c, int nc, unsigned short* __restrict__ oc,
                     const float* __restrict__ d, int nd, unsigned short* __restrict__ od) {
    int stride = gridDim.x * blockDim.x;
    int t = blockIdx.x * blockDim.x + threadIdx.x;
    for (int i = t; i < na; i += stride) oa[i] = f2b(a[i]);
    for (int i = t; i < nb; i += stride) ob[i] = f2b(b[i]);
    for (int i = t; i < nc; i += stride) oc[i] = f2b(c[i]);
    for (int i = t; i < nd; i += stride) od[i] = f2b(d[i]);
}

// ---------------------------------------------------------------------------
// LayerNorm (row of 768), fp32 in -> bf16 out
// ---------------------------------------------------------------------------
__global__ __launch_bounds__(256)
void ln_kernel(const float* __restrict__ x, const float* __restrict__ w,
               const float* __restrict__ bsv, unsigned short* __restrict__ out) {
    int row = blockIdx.x;
    const float* xr = x + (size_t)row * CC;
    float v[3]; float s = 0.f, ss = 0.f;
    #pragma unroll
    for (int i = 0; i < 3; ++i) {
        v[i] = xr[threadIdx.x + i * 256];
        s += v[i]; ss += v[i] * v[i];
    }
    int lane = threadIdx.x & 63, wv = threadIdx.x >> 6;
    #pragma unroll
    for (int off = 32; off; off >>= 1) { s += __shfl_down(s, off); ss += __shfl_down(ss, off); }
    __shared__ float rs[4], rss[4];
    __shared__ float mean_s, rstd_s;
    if (lane == 0) { rs[wv] = s; rss[wv] = ss; }
    __syncthreads();
    if (threadIdx.x == 0) {
        float S = rs[0] + rs[1] + rs[2] + rs[3];
        float SS = rss[0] + rss[1] + rss[2] + rss[3];
        float m = S * (1.0f / 768.0f);
        float var = SS * (1.0f / 768.0f) - m * m;
        mean_s = m; rstd_s = rsqrtf(var + 1e-6f);
    }
    __syncthreads();
    float m = mean_s, r = rstd_s;
    #pragma unroll
    for (int i = 0; i < 3; ++i) {
        int c = threadIdx.x + i * 256;
        out[(size_t)row * CC + c] = f2b((v[i] - m) * r * w[c] + bsv[c]);
    }
}

// ---------------------------------------------------------------------------
// bf16 GEMM: out = epilogue(A(M,K) @ Bw(N,K)^T + bias)
// 128x128 tile, BK=32 panels, 2-deep counted-vmcnt software pipeline (R5):
//   prologue: stage k0->buf0, k1->buf1; vmcnt(4); barrier.
//   iter s: compute buf[s&1] (16 MFMA); s_barrier; restage k(s+2)->buf[s&1];
//           s_waitcnt vmcnt(4) (waits ONLY k(s+1); restage flies across the
//           barrier); s_barrier.  Tail: vmcnt(0).
// Raw __builtin_amdgcn_s_barrier() everywhere -- __syncthreads() would emit
// the vmcnt(0) drain that serialized full HBM latency into every K-step
// (T4/m218: counted-vs-drain0 = +38-73%). LDS stays 32 KB -> 4 blocks/CU
// (R3's occupancy win preserved; avoids m132's 64KB regression).
// EPI 0: bf16 store | 1: fast exact GELU -> bf16 | 2: fp32 store w/ residual
// Launch grid dim3(NT, 152): 152 = 8*ceil(145/8) padded m-rows.
// ---------------------------------------------------------------------------
template <int EPI>
__global__ __launch_bounds__(256, 4)
void gemm_bt(const unsigned short* __restrict__ A, const unsigned short* __restrict__ Bw,
             const float* __restrict__ bias, const float* __restrict__ resid,
             unsigned short* __restrict__ outb, float* __restrict__ outf,
             int M, int N, int K) {
    const int NT = gridDim.x;
    const int MT = (M + 127) >> 7;
    // dispatch-order flat id -> (m_tile, n_tile) with same-XCD A sharing
    int flat = blockIdx.y * NT + blockIdx.x;
    int xcd = flat & 7, s0 = flat >> 3;
    int n_t = s0 % NT, mj = s0 / NT;
    int m_t = xcd + 8 * mj;
    if (m_t >= MT) return;
    const int m0 = m_t * 128, n0 = n_t * 128;

    __shared__ __align__(16) unsigned short As[2][128 * 32];
    __shared__ __align__(16) unsigned short Bs[2][128 * 32];
    const int tid = threadIdx.x;
    const int wave = tid >> 6, lane = tid & 63;
    const int wr = wave >> 1, wc = wave & 1;
    const int quad = lane >> 4, l16 = lane & 15;

    f32x4 acc[4][4] = {};

    // per-thread staging coords (fixed across K): two chunks per panel/matrix
    const int c0 = tid, c1 = 256 + tid;
    const int row0 = c0 >> 2, seg0 = c0 & 3;
    const int row1 = c1 >> 2, seg1 = c1 & 3;
    int gm0 = m0 + row0; if (gm0 > M - 1) gm0 = M - 1;
    int gm1 = m0 + row1; if (gm1 > M - 1) gm1 = M - 1;
    const unsigned short* a0 = A + (size_t)gm0 * K + seg0 * 8;
    const unsigned short* a1 = A + (size_t)gm1 * K + seg1 * 8;
    const unsigned short* b0 = Bw + (size_t)(n0 + row0) * K + seg0 * 8;
    const unsigned short* b1 = Bw + (size_t)(n0 + row1) * K + seg1 * 8;

    const int S = K >> 5;   // 32-wide k-steps; K % 64 == 0 so S >= 2, even

    // prologue: k-step 0 -> buf0, k-step 1 -> buf1
    async16(a0 +  0, &As[0][c0 * 8]);
    async16(a1 +  0, &As[0][c1 * 8]);
    async16(b0 +  0, &Bs[0][c0 * 8]);
    async16(b1 +  0, &Bs[0][c1 * 8]);
    async16(a0 + 32, &As[1][c0 * 8]);
    async16(a1 + 32, &As[1][c1 * 8]);
    async16(b0 + 32, &Bs[1][c0 * 8]);
    async16(b1 + 32, &Bs[1][c1 * 8]);
    asm volatile("s_waitcnt vmcnt(4)" ::: "memory");
    __builtin_amdgcn_s_barrier();

    for (int s = 0; s < S; ++s) {
        const int cur = s & 1;
        bf16x8 bfr[4];
        #pragma unroll
        for (int ni = 0; ni < 4; ++ni)
            bfr[ni] = *(const bf16x8*)&Bs[cur][(wc * 64 + ni * 16 + l16) * 32 + quad * 8];
        #pragma unroll
        for (int mi = 0; mi < 4; ++mi) {
            bf16x8 af = *(const bf16x8*)&As[cur][(wr * 64 + mi * 16 + l16) * 32 + quad * 8];
            #pragma unroll
            for (int ni = 0; ni < 4; ++ni)
                acc[mi][ni] = __builtin_amdgcn_mfma_f32_16x16x32_bf16(af, bfr[ni], acc[mi][ni], 0, 0, 0);
        }
        __builtin_amdgcn_s_barrier();      // all waves done reading buf[cur]
        if (s + 2 < S) {
            const int kk = (s + 2) << 5;
            async16(a0 + kk, &As[cur][c0 * 8]);
            async16(a1 + kk, &As[cur][c1 * 8]);
            async16(b0 + kk, &Bs[cur][c0 * 8]);
            async16(b1 + kk, &Bs[cur][c1 * 8]);
            asm volatile("s_waitcnt vmcnt(4)" ::: "memory");   // k(s+1) landed; restage in flight
        } else {
            asm volatile("s_waitcnt vmcnt(0)" ::: "memory");   // tail: drain
        }
        __builtin_amdgcn_s_barrier();      // buf[cur^1] visible to all waves
    }

    #pragma unroll
    for (int mi = 0; mi < 4; ++mi) {
        #pragma unroll
        for (int r = 0; r < 4; ++r) {
            int grow = m0 + wr * 64 + mi * 16 + quad * 4 + r;   // C/D: row=quad*4+reg
            if (grow >= M) continue;
            #pragma unroll
            for (int ni = 0; ni < 4; ++ni) {
                int gcol = n0 + wc * 64 + ni * 16 + l16;        // C/D: col=lane&15
                float v = acc[mi][ni][r] + bias[gcol];
                size_t idx = (size_t)grow * N + gcol;
                if (EPI == 0) {
                    outb[idx] = f2b(v);
                } else if (EPI == 1) {
                    outb[idx] = f2b(gelu_f(v));
                } else {
                    outf[idx] = resid[idx] + v;
                }
            }
        }
    }
}

// ---------------------------------------------------------------------------
// MFMA flash attention, v4 (R4, verified: attn left top-5, total -27 us).
//  (a) ones-column PV: row-sum of P rides as an extra MFMA column (o5);
//  (b) T14 async-stage split: K/V tile kt+1 loads issue before compute of kt;
//  (c) s_setprio(1) around MFMA clusters.
// LDS 27.6KB: 5 blocks/CU.
// ---------------------------------------------------------------------------
__global__ __launch_bounds__(256)
void attn_mfma(const unsigned short* __restrict__ qkv, const float* __restrict__ aw,
               unsigned short* __restrict__ O, float* __restrict__ patch) {
    const int qt = blockIdx.x, h = blockIdx.y, b = blockIdx.z;
    const int tid = threadIdx.x, wv = tid >> 6, lane = tid & 63;
    const int quad = lane >> 4, l16 = lane & 15;

    __shared__ __align__(16) unsigned short Ks[64 * 72];
    __shared__ __align__(16) unsigned short Vt[64 * 72];
    __shared__ __align__(16) unsigned short Pt[4][16 * 72];

    // Q fragment (A-layout: m=l16, k=quad*8+j), resident, pre-scaled by 2^-3.
    int qrow = qt * 64 + wv * 16 + l16;
    int qclamp = qrow < NN ? qrow : NN - 1;
    const unsigned short* qbase = qkv + (size_t)(b * NN + qclamp) * 2304 + h * 64;
    bf16x8 qf[2];
    qf[0] = *(const bf16x8*)(qbase + quad * 8);
    qf[1] = *(const bf16x8*)(qbase + 32 + quad * 8);
    #pragma unroll
    for (int i = 0; i < 2; ++i) {
        union { bf16x8 v; unsigned short u[8]; } t; t.v = qf[i];
        #pragma unroll
        for (int j = 0; j < 8; ++j) t.u[j] = f2b(b2f(t.u[j]) * 0.125f);
        qf[i] = t.v;
    }

    // ones B-fragment for the l-column: B[n=0][k]=1, else 0.
    union { bf16x8 v; unsigned short u[8]; } onesf;
    #pragma unroll
    for (int j = 0; j < 8; ++j) onesf.u[j] = (l16 == 0) ? (unsigned short)0x3F80 : (unsigned short)0;

    f32x4 o[4] = {};          // O accumulator, C-layout (row=quad*4+r, col d=ni*16+l16)
    f32x4 o5 = {};            // l accumulator (col 0 = row-sum of P)
    float mst[4];             // per-row running max (rows quad*4+r)
    #pragma unroll
    for (int r = 0; r < 4; ++r) mst[r] = -1.0e30f;

    // per-thread staging coords (fixed across kt)
    int keyc[2], segc[2], swzc[2];
    const unsigned short* kb_base;
    const unsigned short* vb_base;
    {
        int c0 = tid, c1 = 256 + tid;
        keyc[0] = c0 >> 3; segc[0] = c0 & 7;
        keyc[1] = c1 >> 3; segc[1] = c1 & 7;
        #pragma unroll
        for (int i = 0; i < 2; ++i) {
            int kg = keyc[i] >> 3, kl = keyc[i] & 7;
            swzc[i] = (kg ^ segc[i]) * 8 + kl;
        }
        kb_base = qkv + (size_t)b * NN * 2304 + 768 + h * 64;
        vb_base = qkv + (size_t)b * NN * 2304 + 1536 + h * 64;
    }

    // prefetch tile 0 into regs
    bf16x8 pk[2], pv[2];
    #pragma unroll
    for (int i = 0; i < 2; ++i) {
        int gk = keyc[i]; if (gk >= NN) gk = NN - 1;   // kt=0: always < NN
        pk[i] = *(const bf16x8*)(kb_base + (size_t)gk * 2304 + segc[i] * 8);
        pv[i] = *(const bf16x8*)(vb_base + (size_t)gk * 2304 + segc[i] * 8);
    }

    for (int kt = 0; kt < 10; ++kt) {
        __syncthreads();   // previous tile's Ks/Vt/Pt reads done before overwrite
        // ---- scatter prefetched K tile [key][d], V transposed+swizzled [d][key'] ----
        #pragma unroll
        for (int i = 0; i < 2; ++i) {
            *(bf16x8*)&Ks[keyc[i] * 72 + segc[i] * 8] = pk[i];
            union { bf16x8 v; unsigned short u[8]; } t; t.v = pv[i];
            #pragma unroll
            for (int e = 0; e < 8; ++e)
                Vt[(segc[i] * 8 + e) * 72 + swzc[i]] = t.u[e];
        }
        __syncthreads();

        // ---- issue next tile's loads early (consumed after next barrier) ----
        if (kt < 9) {
            #pragma unroll
            for (int i = 0; i < 2; ++i) {
                int gk = (kt + 1) * 64 + keyc[i]; if (gk >= NN) gk = NN - 1;
                pk[i] = *(const bf16x8*)(kb_base + (size_t)gk * 2304 + segc[i] * 8);
                pv[i] = *(const bf16x8*)(vb_base + (size_t)gk * 2304 + segc[i] * 8);
            }
        }

        // ---- S = Q K^T (pre-scaled): s[ni][r] = S[quad*4+r][ni*16+l16] ----
        f32x4 s[4];
        __builtin_amdgcn_s_setprio(1);
        #pragma unroll
        for (int ni = 0; ni < 4; ++ni) {
            bf16x8 b0 = *(const bf16x8*)&Ks[(ni * 16 + l16) * 72 + quad * 8];
            bf16x8 b1 = *(const bf16x8*)&Ks[(ni * 16 + l16) * 72 + 32 + quad * 8];
            f32x4 acc = {};
            acc = __builtin_amdgcn_mfma_f32_16x16x32_bf16(qf[0], b0, acc, 0, 0, 0);
            acc = __builtin_amdgcn_mfma_f32_16x16x32_bf16(qf[1], b1, acc, 0, 0, 0);
            s[ni] = acc;
        }
        __builtin_amdgcn_s_setprio(0);

        // ---- mask invalid keys (only last tile; only key 576 is valid) ----
        if (kt == 9) {
            #pragma unroll
            for (int ni = 0; ni < 4; ++ni) {
                if (ni * 16 + l16 != 0) {
                    #pragma unroll
                    for (int r = 0; r < 4; ++r) s[ni][r] = -1.0e30f;
                }
            }
        }

        // ---- row 0 only: patch_attn extraction + attn_weight factor ----
        if (qt == 0 && wv == 0 && quad == 0) {
            #pragma unroll
            for (int ni = 0; ni < 4; ++ni) {
                int gkey = kt * 64 + ni * 16 + l16;
                if (gkey >= 1 && gkey < NN) {
                    patch[(size_t)(b * HH + h) * (NN - 1) + gkey - 1] = s[ni][0];
                    float f = aw[b * (NN - 1) + gkey - 1] * 0.1f + 0.9f;
                    s[ni][0] *= f;
                }
            }
        }

        // ---- online softmax: max via intra-quad butterfly; sums via o5 MFMA ----
        float al[4];
        #pragma unroll
        for (int r = 0; r < 4; ++r) {
            float tm = fmaxf(fmaxf(s[0][r], s[1][r]), fmaxf(s[2][r], s[3][r]));
            tm = fmaxf(tm, __shfl_xor(tm, 1));
            tm = fmaxf(tm, __shfl_xor(tm, 2));
            tm = fmaxf(tm, __shfl_xor(tm, 4));
            tm = fmaxf(tm, __shfl_xor(tm, 8));
            float nm = fmaxf(mst[r], tm);
            al[r] = __expf(mst[r] - nm);   // first tile: exp(-1e30) -> 0
            mst[r] = nm;
        }
        #pragma unroll
        for (int r = 0; r < 4; ++r) {
            #pragma unroll
            for (int ni = 0; ni < 4; ++ni) {
                float p = __expf(s[ni][r] - mst[r]);   // masked: exp(-1e30) -> 0
                Pt[wv][(quad * 4 + r) * 72 + ni * 16 + l16] = f2b(p);
            }
            #pragma unroll
            for (int ni = 0; ni < 4; ++ni) o[ni][r] *= al[r];
            o5[r] *= al[r];
        }

        // ---- O += P V ; l-column += P 1 ----
        __builtin_amdgcn_s_setprio(1);
        #pragma unroll
        for (int kc = 0; kc < 2; ++kc) {
            bf16x8 af = *(const bf16x8*)&Pt[wv][l16 * 72 + kc * 32 + quad * 8];
            #pragma unroll
            for (int ni = 0; ni < 4; ++ni) {
                int d = ni * 16 + l16;
                int gs = (kc * 4 + quad) ^ (d >> 3);   // un-swizzle key group
                bf16x8 vf = *(const bf16x8*)&Vt[d * 72 + gs * 8];
                o[ni] = __builtin_amdgcn_mfma_f32_16x16x32_bf16(af, vf, o[ni], 0, 0, 0);
            }
            o5 = __builtin_amdgcn_mfma_f32_16x16x32_bf16(af, onesf.v, o5, 0, 0, 0);
        }
        __builtin_amdgcn_s_setprio(0);
    }

    // ---- finalize: l for row quad*4+r lives in lane (quad,0) col 0 of o5 ----
    #pragma unroll
    for (int r = 0; r < 4; ++r) {
        float lr = __shfl(o5[r], quad << 4);
        float inv = (lr > 0.f) ? __builtin_amdgcn_rcpf(lr) : 0.f;
        int row = qt * 64 + wv * 16 + quad * 4 + r;
        if (row < NN) {
            #pragma unroll
            for (int ni = 0; ni < 4; ++ni)
                O[(size_t)(b * NN + row) * CC + h * 64 + ni * 16 + l16] = f2b(o[ni][r] * inv);
        }
    }
}

// ---------------------------------------------------------------------------
extern "C" void kernel_launch(void* const* d_in, const int* in_sizes, int n_in,
                              void* d_out, int out_size, void* d_ws, size_t ws_size,
                              hipStream_t stream) {
    const float* x       = (const float*)d_in[0];
    const float* aw      = (const float*)d_in[1];
    const float* ln1w    = (const float*)d_in[2];
    const float* ln1b    = (const float*)d_in[3];
    const float* qkvw_f  = (const float*)d_in[4];
    const float* qkvb    = (const float*)d_in[5];
    const float* projw_f = (const float*)d_in[6];
    const float* projb   = (const float*)d_in[7];
    const float* ln2w    = (const float*)d_in[8];
    const float* ln2b    = (const float*)d_in[9];
    const float* fc1w_f  = (const float*)d_in[10];
    const float* fc1b    = (const float*)d_in[11];
    const float* fc2w_f  = (const float*)d_in[12];
    const float* fc2b    = (const float*)d_in[13];

    // workspace layout (g1 aliases h_bf+qkv, both dead before FC1). ~240 MB.
    char* ws = (char*)d_ws;
    unsigned short* h_bf  = (unsigned short*)(ws + 0);            // 18464x768 bf16
    unsigned short* qkv   = (unsigned short*)(ws + 28360704);     // 18464x2304 bf16
    unsigned short* g1    = (unsigned short*)(ws + 0);            // 18464x3072 bf16 (alias)
    unsigned short* attno = (unsigned short*)(ws + 113442816);    // 18464x768 bf16
    float*          x1    = (float*)(ws + 141803520);             // 18464x768 f32
    unsigned short* h2    = (unsigned short*)(ws + 198524928);    // 18464x768 bf16
    unsigned short* qkvw  = (unsigned short*)(ws + 226885632);    // 2304x768 bf16
    unsigned short* projw = (unsigned short*)(ws + 230424576);    // 768x768 bf16
    unsigned short* fc1w  = (unsigned short*)(ws + 231604224);    // 3072x768 bf16
    unsigned short* fc2w  = (unsigned short*)(ws + 236322816);    // 768x3072 bf16

    float* out_x = (float*)d_out;
    float* out_patch = out_x + (size_t)MROWS * CC;

    // 152 = 8 * ceil(145 m-tiles / 8) -- padded for the XCD swizzle
    cvt4<<<1024, 256, 0, stream>>>(qkvw_f, 2304 * 768, qkvw,
                                   projw_f, 768 * 768, projw,
                                   fc1w_f, 3072 * 768, fc1w,
                                   fc2w_f, 768 * 3072, fc2w);
    ln_kernel<<<MROWS, 256, 0, stream>>>(x, ln1w, ln1b, h_bf);
    gemm_bt<0><<<dim3(18, 152), 256, 0, stream>>>(h_bf, qkvw, qkvb, nullptr, qkv, nullptr,
                                                  MROWS, 2304, 768);
    attn_mfma<<<dim3(10, HH, BB), 256, 0, stream>>>(qkv, aw, attno, out_patch);
    gemm_bt<2><<<dim3(6, 152), 256, 0, stream>>>(attno, projw, projb, x, nullptr, x1,
                                                 MROWS, 768, 768);
    ln_kernel<<<MROWS, 256, 0, stream>>>(x1, ln2w, ln2b, h2);
    gemm_bt<1><<<dim3(24, 152), 256, 0, stream>>>(h2, fc1w, fc1b, nullptr, g1, nullptr,
                                                  MROWS, 3072, 768);
    gemm_bt<2><<<dim3(6, 152), 256, 0, stream>>>(g1, fc2w, fc2b, x1, nullptr, out_x,
                                                 MROWS, 768, 3072);
}

// Round 7
// 699.360 us; speedup vs baseline: 1.0164x; 1.0164x over previous
//
#include <hip/hip_runtime.h>
#include <hip/hip_bf16.h>
#include <cstdint>

#define BB 32
#define NN 577
#define CC 768
#define HH 12
#define HIDN 3072
#define MROWS (BB*NN)   // 18464

typedef __attribute__((ext_vector_type(8))) short bf16x8;   // 8 bf16 = 4 VGPRs
typedef __attribute__((ext_vector_type(4))) float f32x4;

__device__ __forceinline__ float b2f(unsigned short u) {
    union { float f; unsigned int i; } x; x.i = ((unsigned int)u) << 16; return x.f;
}
__device__ __forceinline__ unsigned short f2b(float f) {
    union { float f; unsigned int i; } x; x.f = f;
    unsigned int i = x.i;
    i += 0x7fffu + ((i >> 16) & 1u);   // round-to-nearest-even
    return (unsigned short)(i >> 16);
}

__device__ __forceinline__ void async16(const void* g, void* l) {
    __builtin_amdgcn_global_load_lds(
        (const __attribute__((address_space(1))) uint32_t*)g,
        (__attribute__((address_space(3))) uint32_t*)l, 16, 0, 0);
}

// Fast exact-GELU: erf via Abramowitz-Stegun 7.1.26 (|err|<=1.5e-7),
// rcp + exp are single HW instrs. ~13 VALU vs ~45 for libm erff.
__device__ __forceinline__ float gelu_f(float v) {
    float ax = fabsf(v) * 0.70710678118654752f;
    float t = __builtin_amdgcn_rcpf(1.0f + 0.3275911f * ax);
    float poly = t * (0.254829592f + t * (-0.284496736f + t * (1.421413741f +
                 t * (-1.453152027f + t * 1.061405429f))));
    float e = __expf(-ax * ax);
    float erf_abs = 1.0f - poly * e;
    float erf_v = (v >= 0.f) ? erf_abs : -erf_abs;
    return 0.5f * v * (1.0f + erf_v);
}

// ---------------------------------------------------------------------------
// fp32 -> bf16 weight conversion (4 matrices in one kernel)
// ---------------------------------------------------------------------------
__global__ void cvt4(const float* __restrict__ a, int na, unsigned short* __restrict__ oa,
                     const float* __restrict__ b, int nb, unsigned short* __restrict__ ob,
                     const float* __restrict__ c, int nc, unsigned short* __restrict__ oc,
                     const float* __restrict__ d, int nd, unsigned short* __restrict__ od) {
    int stride = gridDim.x * blockDim.x;
    int t = blockIdx.x * blockDim.x + threadIdx.x;
    for (int i = t; i < na; i += stride) oa[i] = f2b(a[i]);
    for (int i = t; i < nb; i += stride) ob[i] = f2b(b[i]);
    for (int i = t; i < nc; i += stride) oc[i] = f2b(c[i]);
    for (int i = t; i < nd; i += stride) od[i] = f2b(d[i]);
}

// ---------------------------------------------------------------------------
// LayerNorm (row of 768), fp32 in -> bf16 out
// ---------------------------------------------------------------------------
__global__ __launch_bounds__(256)
void ln_kernel(const float* __restrict__ x, const float* __restrict__ w,
               const float* __restrict__ bsv, unsigned short* __restrict__ out) {
    int row = blockIdx.x;
    const float* xr = x + (size_t)row * CC;
    float v[3]; float s = 0.f, ss = 0.f;
    #pragma unroll
    for (int i = 0; i < 3; ++i) {
        v[i] = xr[threadIdx.x + i * 256];
        s += v[i]; ss += v[i] * v[i];
    }
    int lane = threadIdx.x & 63, wv = threadIdx.x >> 6;
    #pragma unroll
    for (int off = 32; off; off >>= 1) { s += __shfl_down(s, off); ss += __shfl_down(ss, off); }
    __shared__ float rs[4], rss[4];
    __shared__ float mean_s, rstd_s;
    if (lane == 0) { rs[wv] = s; rss[wv] = ss; }
    __syncthreads();
    if (threadIdx.x == 0) {
        float S = rs[0] + rs[1] + rs[2] + rs[3];
        float SS = rss[0] + rss[1] + rss[2] + rss[3];
        float m = S * (1.0f / 768.0f);
        float var = SS * (1.0f / 768.0f) - m * m;
        mean_s = m; rstd_s = rsqrtf(var + 1e-6f);
    }
    __syncthreads();
    float m = mean_s, r = rstd_s;
    #pragma unroll
    for (int i = 0; i < 3; ++i) {
        int c = threadIdx.x + i * 256;
        out[(size_t)row * CC + c] = f2b((v[i] - m) * r * w[c] + bsv[c]);
    }
}

// ---------------------------------------------------------------------------
// bf16 GEMM: out = epilogue(A(M,K) @ Bw(N,K)^T + bias)
// 128x128 tile, BK=32 panels, minimum-2-phase template (R6; T3 recipe):
//   prologue: stage panel0 -> buf0; vmcnt(0); barrier.
//   iter s: ISSUE stage panel s+1 -> buf[cur^1] FIRST (readers of that buffer
//           finished at iter s-1's barrier), then ds_read + 16 MFMA on
//           buf[cur], then vmcnt(0) + s_barrier.  Last iter: compute only.
// The vmcnt wait is covered by a full panel of compute (vs R4 where the
// drain sat between stage and compute with latency fully exposed; vs R5
// which doubled barriers and halved the covering compute -- regressed).
// One barrier per panel. LDS 32 KB -> 4 blocks/CU (R3 occupancy preserved).
// EPI 0: bf16 store | 1: fast exact GELU -> bf16 | 2: fp32 store w/ residual
// Launch grid dim3(NT, 152): 152 = 8*ceil(145/8) padded m-rows.
// ---------------------------------------------------------------------------
template <int EPI>
__global__ __launch_bounds__(256, 4)
void gemm_bt(const unsigned short* __restrict__ A, const unsigned short* __restrict__ Bw,
             const float* __restrict__ bias, const float* __restrict__ resid,
             unsigned short* __restrict__ outb, float* __restrict__ outf,
             int M, int N, int K) {
    const int NT = gridDim.x;
    const int MT = (M + 127) >> 7;
    // dispatch-order flat id -> (m_tile, n_tile) with same-XCD A sharing
    int flat = blockIdx.y * NT + blockIdx.x;
    int xcd = flat & 7, s0 = flat >> 3;
    int n_t = s0 % NT, mj = s0 / NT;
    int m_t = xcd + 8 * mj;
    if (m_t >= MT) return;
    const int m0 = m_t * 128, n0 = n_t * 128;

    __shared__ __align__(16) unsigned short As[2][128 * 32];
    __shared__ __align__(16) unsigned short Bs[2][128 * 32];
    const int tid = threadIdx.x;
    const int wave = tid >> 6, lane = tid & 63;
    const int wr = wave >> 1, wc = wave & 1;
    const int quad = lane >> 4, l16 = lane & 15;

    f32x4 acc[4][4] = {};

    // per-thread staging coords (fixed across K): two chunks per panel/matrix
    const int c0 = tid, c1 = 256 + tid;
    const int row0 = c0 >> 2, seg0 = c0 & 3;
    const int row1 = c1 >> 2, seg1 = c1 & 3;
    int gm0 = m0 + row0; if (gm0 > M - 1) gm0 = M - 1;
    int gm1 = m0 + row1; if (gm1 > M - 1) gm1 = M - 1;
    const unsigned short* a0 = A + (size_t)gm0 * K + seg0 * 8;
    const unsigned short* a1 = A + (size_t)gm1 * K + seg1 * 8;
    const unsigned short* b0 = Bw + (size_t)(n0 + row0) * K + seg0 * 8;
    const unsigned short* b1 = Bw + (size_t)(n0 + row1) * K + seg1 * 8;

    const int S = K >> 5;   // 32-wide k-steps

    // prologue: panel 0 -> buf0
    async16(a0, &As[0][c0 * 8]);
    async16(a1, &As[0][c1 * 8]);
    async16(b0, &Bs[0][c0 * 8]);
    async16(b1, &Bs[0][c1 * 8]);
    asm volatile("s_waitcnt vmcnt(0)" ::: "memory");
    __builtin_amdgcn_s_barrier();

    for (int s = 0; s < S; ++s) {
        const int cur = s & 1;
        // issue next panel's loads FIRST -- they fly across this panel's compute
        if (s + 1 < S) {
            const int kk = (s + 1) << 5;
            async16(a0 + kk, &As[cur ^ 1][c0 * 8]);
            async16(a1 + kk, &As[cur ^ 1][c1 * 8]);
            async16(b0 + kk, &Bs[cur ^ 1][c0 * 8]);
            async16(b1 + kk, &Bs[cur ^ 1][c1 * 8]);
        }
        bf16x8 bfr[4];
        #pragma unroll
        for (int ni = 0; ni < 4; ++ni)
            bfr[ni] = *(const bf16x8*)&Bs[cur][(wc * 64 + ni * 16 + l16) * 32 + quad * 8];
        #pragma unroll
        for (int mi = 0; mi < 4; ++mi) {
            bf16x8 af = *(const bf16x8*)&As[cur][(wr * 64 + mi * 16 + l16) * 32 + quad * 8];
            #pragma unroll
            for (int ni = 0; ni < 4; ++ni)
                acc[mi][ni] = __builtin_amdgcn_mfma_f32_16x16x32_bf16(af, bfr[ni], acc[mi][ni], 0, 0, 0);
        }
        if (s + 1 < S) {
            asm volatile("s_waitcnt vmcnt(0)" ::: "memory");   // panel s+1 landed
            __builtin_amdgcn_s_barrier();                      // visible to all waves
        }
    }

    #pragma unroll
    for (int mi = 0; mi < 4; ++mi) {
        #pragma unroll
        for (int r = 0; r < 4; ++r) {
            int grow = m0 + wr * 64 + mi * 16 + quad * 4 + r;   // C/D: row=quad*4+reg
            if (grow >= M) continue;
            #pragma unroll
            for (int ni = 0; ni < 4; ++ni) {
                int gcol = n0 + wc * 64 + ni * 16 + l16;        // C/D: col=lane&15
                float v = acc[mi][ni][r] + bias[gcol];
                size_t idx = (size_t)grow * N + gcol;
                if (EPI == 0) {
                    outb[idx] = f2b(v);
                } else if (EPI == 1) {
                    outb[idx] = f2b(gelu_f(v));
                } else {
                    outf[idx] = resid[idx] + v;
                }
            }
        }
    }
}

// ---------------------------------------------------------------------------
// MFMA flash attention, v4 (R4, verified: attn left top-5, total -27 us).
//  (a) ones-column PV: row-sum of P rides as an extra MFMA column (o5);
//  (b) T14 async-stage split: K/V tile kt+1 loads issue before compute of kt;
//  (c) s_setprio(1) around MFMA clusters.
// LDS 27.6KB: 5 blocks/CU.
// ---------------------------------------------------------------------------
__global__ __launch_bounds__(256)
void attn_mfma(const unsigned short* __restrict__ qkv, const float* __restrict__ aw,
               unsigned short* __restrict__ O, float* __restrict__ patch) {
    const int qt = blockIdx.x, h = blockIdx.y, b = blockIdx.z;
    const int tid = threadIdx.x, wv = tid >> 6, lane = tid & 63;
    const int quad = lane >> 4, l16 = lane & 15;

    __shared__ __align__(16) unsigned short Ks[64 * 72];
    __shared__ __align__(16) unsigned short Vt[64 * 72];
    __shared__ __align__(16) unsigned short Pt[4][16 * 72];

    // Q fragment (A-layout: m=l16, k=quad*8+j), resident, pre-scaled by 2^-3.
    int qrow = qt * 64 + wv * 16 + l16;
    int qclamp = qrow < NN ? qrow : NN - 1;
    const unsigned short* qbase = qkv + (size_t)(b * NN + qclamp) * 2304 + h * 64;
    bf16x8 qf[2];
    qf[0] = *(const bf16x8*)(qbase + quad * 8);
    qf[1] = *(const bf16x8*)(qbase + 32 + quad * 8);
    #pragma unroll
    for (int i = 0; i < 2; ++i) {
        union { bf16x8 v; unsigned short u[8]; } t; t.v = qf[i];
        #pragma unroll
        for (int j = 0; j < 8; ++j) t.u[j] = f2b(b2f(t.u[j]) * 0.125f);
        qf[i] = t.v;
    }

    // ones B-fragment for the l-column: B[n=0][k]=1, else 0.
    union { bf16x8 v; unsigned short u[8]; } onesf;
    #pragma unroll
    for (int j = 0; j < 8; ++j) onesf.u[j] = (l16 == 0) ? (unsigned short)0x3F80 : (unsigned short)0;

    f32x4 o[4] = {};          // O accumulator, C-layout (row=quad*4+r, col d=ni*16+l16)
    f32x4 o5 = {};            // l accumulator (col 0 = row-sum of P)
    float mst[4];             // per-row running max (rows quad*4+r)
    #pragma unroll
    for (int r = 0; r < 4; ++r) mst[r] = -1.0e30f;

    // per-thread staging coords (fixed across kt)
    int keyc[2], segc[2], swzc[2];
    const unsigned short* kb_base;
    const unsigned short* vb_base;
    {
        int c0 = tid, c1 = 256 + tid;
        keyc[0] = c0 >> 3; segc[0] = c0 & 7;
        keyc[1] = c1 >> 3; segc[1] = c1 & 7;
        #pragma unroll
        for (int i = 0; i < 2; ++i) {
            int kg = keyc[i] >> 3, kl = keyc[i] & 7;
            swzc[i] = (kg ^ segc[i]) * 8 + kl;
        }
        kb_base = qkv + (size_t)b * NN * 2304 + 768 + h * 64;
        vb_base = qkv + (size_t)b * NN * 2304 + 1536 + h * 64;
    }

    // prefetch tile 0 into regs
    bf16x8 pk[2], pv[2];
    #pragma unroll
    for (int i = 0; i < 2; ++i) {
        int gk = keyc[i]; if (gk >= NN) gk = NN - 1;   // kt=0: always < NN
        pk[i] = *(const bf16x8*)(kb_base + (size_t)gk * 2304 + segc[i] * 8);
        pv[i] = *(const bf16x8*)(vb_base + (size_t)gk * 2304 + segc[i] * 8);
    }

    for (int kt = 0; kt < 10; ++kt) {
        __syncthreads();   // previous tile's Ks/Vt/Pt reads done before overwrite
        // ---- scatter prefetched K tile [key][d], V transposed+swizzled [d][key'] ----
        #pragma unroll
        for (int i = 0; i < 2; ++i) {
            *(bf16x8*)&Ks[keyc[i] * 72 + segc[i] * 8] = pk[i];
            union { bf16x8 v; unsigned short u[8]; } t; t.v = pv[i];
            #pragma unroll
            for (int e = 0; e < 8; ++e)
                Vt[(segc[i] * 8 + e) * 72 + swzc[i]] = t.u[e];
        }
        __syncthreads();

        // ---- issue next tile's loads early (consumed after next barrier) ----
        if (kt < 9) {
            #pragma unroll
            for (int i = 0; i < 2; ++i) {
                int gk = (kt + 1) * 64 + keyc[i]; if (gk >= NN) gk = NN - 1;
                pk[i] = *(const bf16x8*)(kb_base + (size_t)gk * 2304 + segc[i] * 8);
                pv[i] = *(const bf16x8*)(vb_base + (size_t)gk * 2304 + segc[i] * 8);
            }
        }

        // ---- S = Q K^T (pre-scaled): s[ni][r] = S[quad*4+r][ni*16+l16] ----
        f32x4 s[4];
        __builtin_amdgcn_s_setprio(1);
        #pragma unroll
        for (int ni = 0; ni < 4; ++ni) {
            bf16x8 b0 = *(const bf16x8*)&Ks[(ni * 16 + l16) * 72 + quad * 8];
            bf16x8 b1 = *(const bf16x8*)&Ks[(ni * 16 + l16) * 72 + 32 + quad * 8];
            f32x4 acc = {};
            acc = __builtin_amdgcn_mfma_f32_16x16x32_bf16(qf[0], b0, acc, 0, 0, 0);
            acc = __builtin_amdgcn_mfma_f32_16x16x32_bf16(qf[1], b1, acc, 0, 0, 0);
            s[ni] = acc;
        }
        __builtin_amdgcn_s_setprio(0);

        // ---- mask invalid keys (only last tile; only key 576 is valid) ----
        if (kt == 9) {
            #pragma unroll
            for (int ni = 0; ni < 4; ++ni) {
                if (ni * 16 + l16 != 0) {
                    #pragma unroll
                    for (int r = 0; r < 4; ++r) s[ni][r] = -1.0e30f;
                }
            }
        }

        // ---- row 0 only: patch_attn extraction + attn_weight factor ----
        if (qt == 0 && wv == 0 && quad == 0) {
            #pragma unroll
            for (int ni = 0; ni < 4; ++ni) {
                int gkey = kt * 64 + ni * 16 + l16;
                if (gkey >= 1 && gkey < NN) {
                    patch[(size_t)(b * HH + h) * (NN - 1) + gkey - 1] = s[ni][0];
                    float f = aw[b * (NN - 1) + gkey - 1] * 0.1f + 0.9f;
                    s[ni][0] *= f;
                }
            }
        }

        // ---- online softmax: max via intra-quad butterfly; sums via o5 MFMA ----
        float al[4];
        #pragma unroll
        for (int r = 0; r < 4; ++r) {
            float tm = fmaxf(fmaxf(s[0][r], s[1][r]), fmaxf(s[2][r], s[3][r]));
            tm = fmaxf(tm, __shfl_xor(tm, 1));
            tm = fmaxf(tm, __shfl_xor(tm, 2));
            tm = fmaxf(tm, __shfl_xor(tm, 4));
            tm = fmaxf(tm, __shfl_xor(tm, 8));
            float nm = fmaxf(mst[r], tm);
            al[r] = __expf(mst[r] - nm);   // first tile: exp(-1e30) -> 0
            mst[r] = nm;
        }
        #pragma unroll
        for (int r = 0; r < 4; ++r) {
            #pragma unroll
            for (int ni = 0; ni < 4; ++ni) {
                float p = __expf(s[ni][r] - mst[r]);   // masked: exp(-1e30) -> 0
                Pt[wv][(quad * 4 + r) * 72 + ni * 16 + l16] = f2b(p);
            }
            #pragma unroll
            for (int ni = 0; ni < 4; ++ni) o[ni][r] *= al[r];
            o5[r] *= al[r];
        }

        // ---- O += P V ; l-column += P 1 ----
        __builtin_amdgcn_s_setprio(1);
        #pragma unroll
        for (int kc = 0; kc < 2; ++kc) {
            bf16x8 af = *(const bf16x8*)&Pt[wv][l16 * 72 + kc * 32 + quad * 8];
            #pragma unroll
            for (int ni = 0; ni < 4; ++ni) {
                int d = ni * 16 + l16;
                int gs = (kc * 4 + quad) ^ (d >> 3);   // un-swizzle key group
                bf16x8 vf = *(const bf16x8*)&Vt[d * 72 + gs * 8];
                o[ni] = __builtin_amdgcn_mfma_f32_16x16x32_bf16(af, vf, o[ni], 0, 0, 0);
            }
            o5 = __builtin_amdgcn_mfma_f32_16x16x32_bf16(af, onesf.v, o5, 0, 0, 0);
        }
        __builtin_amdgcn_s_setprio(0);
    }

    // ---- finalize: l for row quad*4+r lives in lane (quad,0) col 0 of o5 ----
    #pragma unroll
    for (int r = 0; r < 4; ++r) {
        float lr = __shfl(o5[r], quad << 4);
        float inv = (lr > 0.f) ? __builtin_amdgcn_rcpf(lr) : 0.f;
        int row = qt * 64 + wv * 16 + quad * 4 + r;
        if (row < NN) {
            #pragma unroll
            for (int ni = 0; ni < 4; ++ni)
                O[(size_t)(b * NN + row) * CC + h * 64 + ni * 16 + l16] = f2b(o[ni][r] * inv);
        }
    }
}

// ---------------------------------------------------------------------------
extern "C" void kernel_launch(void* const* d_in, const int* in_sizes, int n_in,
                              void* d_out, int out_size, void* d_ws, size_t ws_size,
                              hipStream_t stream) {
    const float* x       = (const float*)d_in[0];
    const float* aw      = (const float*)d_in[1];
    const float* ln1w    = (const float*)d_in[2];
    const float* ln1b    = (const float*)d_in[3];
    const float* qkvw_f  = (const float*)d_in[4];
    const float* qkvb    = (const float*)d_in[5];
    const float* projw_f = (const float*)d_in[6];
    const float* projb   = (const float*)d_in[7];
    const float* ln2w    = (const float*)d_in[8];
    const float* ln2b    = (const float*)d_in[9];
    const float* fc1w_f  = (const float*)d_in[10];
    const float* fc1b    = (const float*)d_in[11];
    const float* fc2w_f  = (const float*)d_in[12];
    const float* fc2b    = (const float*)d_in[13];

    // workspace layout (g1 aliases h_bf+qkv, both dead before FC1). ~240 MB.
    char* ws = (char*)d_ws;
    unsigned short* h_bf  = (unsigned short*)(ws + 0);            // 18464x768 bf16
    unsigned short* qkv   = (unsigned short*)(ws + 28360704);     // 18464x2304 bf16
    unsigned short* g1    = (unsigned short*)(ws + 0);            // 18464x3072 bf16 (alias)
    unsigned short* attno = (unsigned short*)(ws + 113442816);    // 18464x768 bf16
    float*          x1    = (float*)(ws + 141803520);             // 18464x768 f32
    unsigned short* h2    = (unsigned short*)(ws + 198524928);    // 18464x768 bf16
    unsigned short* qkvw  = (unsigned short*)(ws + 226885632);    // 2304x768 bf16
    unsigned short* projw = (unsigned short*)(ws + 230424576);    // 768x768 bf16
    unsigned short* fc1w  = (unsigned short*)(ws + 231604224);    // 3072x768 bf16
    unsigned short* fc2w  = (unsigned short*)(ws + 236322816);    // 768x3072 bf16

    float* out_x = (float*)d_out;
    float* out_patch = out_x + (size_t)MROWS * CC;

    // 152 = 8 * ceil(145 m-tiles / 8) -- padded for the XCD swizzle
    cvt4<<<1024, 256, 0, stream>>>(qkvw_f, 2304 * 768, qkvw,
                                   projw_f, 768 * 768, projw,
                                   fc1w_f, 3072 * 768, fc1w,
                                   fc2w_f, 768 * 3072, fc2w);
    ln_kernel<<<MROWS, 256, 0, stream>>>(x, ln1w, ln1b, h_bf);
    gemm_bt<0><<<dim3(18, 152), 256, 0, stream>>>(h_bf, qkvw, qkvb, nullptr, qkv, nullptr,
                                                  MROWS, 2304, 768);
    attn_mfma<<<dim3(10, HH, BB), 256, 0, stream>>>(qkv, aw, attno, out_patch);
    gemm_bt<2><<<dim3(6, 152), 256, 0, stream>>>(attno, projw, projb, x, nullptr, x1,
                                                 MROWS, 768, 768);
    ln_kernel<<<MROWS, 256, 0, stream>>>(x1, ln2w, ln2b, h2);
    gemm_bt<1><<<dim3(24, 152), 256, 0, stream>>>(h2, fc1w, fc1b, nullptr, g1, nullptr,
                                                  MROWS, 3072, 768);
    gemm_bt<2><<<dim3(6, 152), 256, 0, stream>>>(g1, fc2w, fc2b, x1, nullptr, out_x,
                                                 MROWS, 768, 3072);
}

// Round 8
// 669.916 us; speedup vs baseline: 1.0611x; 1.0440x over previous
//
#include <hip/hip_runtime.h>
#include <hip/hip_bf16.h>
#include <cstdint>

#define BB 32
#define NN 577
#define CC 768
#define HH 12
#define HIDN 3072
#define MROWS (BB*NN)   // 18464

typedef __attribute__((ext_vector_type(8))) short bf16x8;   // 8 bf16 = 4 VGPRs
typedef __attribute__((ext_vector_type(4))) float f32x4;

__device__ __forceinline__ float b2f(unsigned short u) {
    union { float f; unsigned int i; } x; x.i = ((unsigned int)u) << 16; return x.f;
}
__device__ __forceinline__ unsigned short f2b(float f) {
    union { float f; unsigned int i; } x; x.f = f;
    unsigned int i = x.i;
    i += 0x7fffu + ((i >> 16) & 1u);   // round-to-nearest-even
    return (unsigned short)(i >> 16);
}

__device__ __forceinline__ void async16(const void* g, void* l) {
    __builtin_amdgcn_global_load_lds(
        (const __attribute__((address_space(1))) uint32_t*)g,
        (__attribute__((address_space(3))) uint32_t*)l, 16, 0, 0);
}

// Fast exact-GELU: erf via Abramowitz-Stegun 7.1.26 (|err|<=1.5e-7),
// rcp + exp are single HW instrs. ~13 VALU vs ~45 for libm erff.
__device__ __forceinline__ float gelu_f(float v) {
    float ax = fabsf(v) * 0.70710678118654752f;
    float t = __builtin_amdgcn_rcpf(1.0f + 0.3275911f * ax);
    float poly = t * (0.254829592f + t * (-0.284496736f + t * (1.421413741f +
                 t * (-1.453152027f + t * 1.061405429f))));
    float e = __expf(-ax * ax);
    float erf_abs = 1.0f - poly * e;
    float erf_v = (v >= 0.f) ? erf_abs : -erf_abs;
    return 0.5f * v * (1.0f + erf_v);
}

// ---------------------------------------------------------------------------
// fp32 -> bf16 weight conversion, float4/ushort4 vectorized (R7: G13 —
// scalar f32 loads were 4B/lane; 16B/lane quadruples per-instr bytes).
// All matrix element counts are divisible by 4.
// ---------------------------------------------------------------------------
__global__ void cvt4(const float* __restrict__ a, int na, unsigned short* __restrict__ oa,
                     const float* __restrict__ b, int nb, unsigned short* __restrict__ ob,
                     const float* __restrict__ c, int nc, unsigned short* __restrict__ oc,
                     const float* __restrict__ d, int nd, unsigned short* __restrict__ od) {
    int stride = gridDim.x * blockDim.x;
    int t = blockIdx.x * blockDim.x + threadIdx.x;
    for (int i = t; i < (na >> 2); i += stride) {
        float4 f = ((const float4*)a)[i];
        ushort4 o = { f2b(f.x), f2b(f.y), f2b(f.z), f2b(f.w) };
        ((ushort4*)oa)[i] = o;
    }
    for (int i = t; i < (nb >> 2); i += stride) {
        float4 f = ((const float4*)b)[i];
        ushort4 o = { f2b(f.x), f2b(f.y), f2b(f.z), f2b(f.w) };
        ((ushort4*)ob)[i] = o;
    }
    for (int i = t; i < (nc >> 2); i += stride) {
        float4 f = ((const float4*)c)[i];
        ushort4 o = { f2b(f.x), f2b(f.y), f2b(f.z), f2b(f.w) };
        ((ushort4*)oc)[i] = o;
    }
    for (int i = t; i < (nd >> 2); i += stride) {
        float4 f = ((const float4*)d)[i];
        ushort4 o = { f2b(f.x), f2b(f.y), f2b(f.z), f2b(f.w) };
        ((ushort4*)od)[i] = o;
    }
}

// ---------------------------------------------------------------------------
// LayerNorm (row of 768), fp32 in -> bf16 out.  R7 rewrite: one WAVE per row
// (4 rows/block, grid MROWS/4) — float4 loads (16B/lane), 64-wide shfl_xor
// butterfly, ushort4 stores. No LDS, no barriers (was: scalar loads + LDS
// cross-wave reduce + 2 syncthreads). 85 MB traffic -> ~13.5 us floor.
// ---------------------------------------------------------------------------
__global__ __launch_bounds__(256)
void ln_kernel(const float* __restrict__ x, const float* __restrict__ w,
               const float* __restrict__ bsv, unsigned short* __restrict__ out) {
    const int lane = threadIdx.x & 63, wv = threadIdx.x >> 6;
    const int row = blockIdx.x * 4 + wv;
    const float* xr = x + (size_t)row * CC;
    float4 v[3]; float s = 0.f, ss = 0.f;
    #pragma unroll
    for (int i = 0; i < 3; ++i) {
        v[i] = *(const float4*)&xr[(lane + i * 64) * 4];
        s  += v[i].x + v[i].y + v[i].z + v[i].w;
        ss += v[i].x * v[i].x + v[i].y * v[i].y + v[i].z * v[i].z + v[i].w * v[i].w;
    }
    #pragma unroll
    for (int off = 32; off; off >>= 1) { s += __shfl_xor(s, off); ss += __shfl_xor(ss, off); }
    float m = s * (1.0f / 768.0f);
    float r = rsqrtf(ss * (1.0f / 768.0f) - m * m + 1e-6f);
    #pragma unroll
    for (int i = 0; i < 3; ++i) {
        int c = (lane + i * 64) * 4;
        float4 wv4 = *(const float4*)&w[c];
        float4 bv4 = *(const float4*)&bsv[c];
        ushort4 o;
        o.x = f2b((v[i].x - m) * r * wv4.x + bv4.x);
        o.y = f2b((v[i].y - m) * r * wv4.y + bv4.y);
        o.z = f2b((v[i].z - m) * r * wv4.z + bv4.z);
        o.w = f2b((v[i].w - m) * r * wv4.w + bv4.w);
        *(ushort4*)&out[(size_t)row * CC + c] = o;
    }
}

// ---------------------------------------------------------------------------
// bf16 GEMM: out = epilogue(A(M,K) @ Bw(N,K)^T + bias)
// m97 structure, BK=64 as two 32-wide panels (As[2]/Bs[2], 32 KB LDS).
// __launch_bounds__(256,4) -> <=128 unified regs/wave -> 4 blocks/CU (R3/R4,
// verified). R7 NOTE: both source-level pipelining attempts (R5 counted-vmcnt
// 2-deep; R6 issue-first 2-phase) REGRESSED vs this simple structure
// (143.5 -> 149.8 / 154.2 us on FC1) — reproduces learn_hip m99/m131-m140:
// at >=4 blocks/CU, inter-block TLP already hides the syncthreads drain;
// do NOT re-attempt source pipelining on this structure.
// EPI 0: bf16 store | 1: fast exact GELU -> bf16 | 2: fp32 store w/ residual
// Launch grid dim3(NT, 152): 152 = 8*ceil(145/8) padded m-rows.
// ---------------------------------------------------------------------------
template <int EPI>
__global__ __launch_bounds__(256, 4)
void gemm_bt(const unsigned short* __restrict__ A, const unsigned short* __restrict__ Bw,
             const float* __restrict__ bias, const float* __restrict__ resid,
             unsigned short* __restrict__ outb, float* __restrict__ outf,
             int M, int N, int K) {
    const int NT = gridDim.x;
    const int MT = (M + 127) >> 7;
    // dispatch-order flat id -> (m_tile, n_tile) with same-XCD A sharing
    int flat = blockIdx.y * NT + blockIdx.x;
    int xcd = flat & 7, s = flat >> 3;
    int n_t = s % NT, mj = s / NT;
    int m_t = xcd + 8 * mj;
    if (m_t >= MT) return;
    const int m0 = m_t * 128, n0 = n_t * 128;

    __shared__ __align__(16) unsigned short As[2][128 * 32];
    __shared__ __align__(16) unsigned short Bs[2][128 * 32];
    const int tid = threadIdx.x;
    const int wave = tid >> 6, lane = tid & 63;
    const int wr = wave >> 1, wc = wave & 1;
    const int quad = lane >> 4, l16 = lane & 15;

    f32x4 acc[4][4] = {};

    // per-thread staging coords (fixed across K): two chunks per panel/matrix
    const int c0 = tid, c1 = 256 + tid;
    const int row0 = c0 >> 2, seg0 = c0 & 3;
    const int row1 = c1 >> 2, seg1 = c1 & 3;
    int gm0 = m0 + row0; if (gm0 > M - 1) gm0 = M - 1;
    int gm1 = m0 + row1; if (gm1 > M - 1) gm1 = M - 1;
    const unsigned short* a0 = A + (size_t)gm0 * K + seg0 * 8;
    const unsigned short* a1 = A + (size_t)gm1 * K + seg1 * 8;
    const unsigned short* b0 = Bw + (size_t)(n0 + row0) * K + seg0 * 8;
    const unsigned short* b1 = Bw + (size_t)(n0 + row1) * K + seg1 * 8;

    for (int k0 = 0; k0 < K; k0 += 64) {
        #pragma unroll
        for (int p = 0; p < 2; ++p) {
            int kk = k0 + p * 32;
            async16(a0 + kk, &As[p][c0 * 8]);
            async16(a1 + kk, &As[p][c1 * 8]);
            async16(b0 + kk, &Bs[p][c0 * 8]);
            async16(b1 + kk, &Bs[p][c1 * 8]);
        }
        __syncthreads();
        #pragma unroll
        for (int p = 0; p < 2; ++p) {
            bf16x8 bfr[4];
            #pragma unroll
            for (int ni = 0; ni < 4; ++ni)
                bfr[ni] = *(const bf16x8*)&Bs[p][(wc * 64 + ni * 16 + l16) * 32 + quad * 8];
            #pragma unroll
            for (int mi = 0; mi < 4; ++mi) {
                bf16x8 af = *(const bf16x8*)&As[p][(wr * 64 + mi * 16 + l16) * 32 + quad * 8];
                #pragma unroll
                for (int ni = 0; ni < 4; ++ni)
                    acc[mi][ni] = __builtin_amdgcn_mfma_f32_16x16x32_bf16(af, bfr[ni], acc[mi][ni], 0, 0, 0);
            }
        }
        __syncthreads();
    }

    #pragma unroll
    for (int mi = 0; mi < 4; ++mi) {
        #pragma unroll
        for (int r = 0; r < 4; ++r) {
            int grow = m0 + wr * 64 + mi * 16 + quad * 4 + r;   // C/D: row=quad*4+reg
            if (grow >= M) continue;
            #pragma unroll
            for (int ni = 0; ni < 4; ++ni) {
                int gcol = n0 + wc * 64 + ni * 16 + l16;        // C/D: col=lane&15
                float v = acc[mi][ni][r] + bias[gcol];
                size_t idx = (size_t)grow * N + gcol;
                if (EPI == 0) {
                    outb[idx] = f2b(v);
                } else if (EPI == 1) {
                    outb[idx] = f2b(gelu_f(v));
                } else {
                    outf[idx] = resid[idx] + v;
                }
            }
        }
    }
}

// ---------------------------------------------------------------------------
// MFMA flash attention, v4 (R4, verified: attn left top-5, total -27 us).
//  (a) ones-column PV: row-sum of P rides as an extra MFMA column (o5);
//  (b) T14 async-stage split: K/V tile kt+1 loads issue before compute of kt;
//  (c) s_setprio(1) around MFMA clusters.
// LDS 27.6KB: 5 blocks/CU.
// ---------------------------------------------------------------------------
__global__ __launch_bounds__(256)
void attn_mfma(const unsigned short* __restrict__ qkv, const float* __restrict__ aw,
               unsigned short* __restrict__ O, float* __restrict__ patch) {
    const int qt = blockIdx.x, h = blockIdx.y, b = blockIdx.z;
    const int tid = threadIdx.x, wv = tid >> 6, lane = tid & 63;
    const int quad = lane >> 4, l16 = lane & 15;

    __shared__ __align__(16) unsigned short Ks[64 * 72];
    __shared__ __align__(16) unsigned short Vt[64 * 72];
    __shared__ __align__(16) unsigned short Pt[4][16 * 72];

    // Q fragment (A-layout: m=l16, k=quad*8+j), resident, pre-scaled by 2^-3.
    int qrow = qt * 64 + wv * 16 + l16;
    int qclamp = qrow < NN ? qrow : NN - 1;
    const unsigned short* qbase = qkv + (size_t)(b * NN + qclamp) * 2304 + h * 64;
    bf16x8 qf[2];
    qf[0] = *(const bf16x8*)(qbase + quad * 8);
    qf[1] = *(const bf16x8*)(qbase + 32 + quad * 8);
    #pragma unroll
    for (int i = 0; i < 2; ++i) {
        union { bf16x8 v; unsigned short u[8]; } t; t.v = qf[i];
        #pragma unroll
        for (int j = 0; j < 8; ++j) t.u[j] = f2b(b2f(t.u[j]) * 0.125f);
        qf[i] = t.v;
    }

    // ones B-fragment for the l-column: B[n=0][k]=1, else 0.
    union { bf16x8 v; unsigned short u[8]; } onesf;
    #pragma unroll
    for (int j = 0; j < 8; ++j) onesf.u[j] = (l16 == 0) ? (unsigned short)0x3F80 : (unsigned short)0;

    f32x4 o[4] = {};          // O accumulator, C-layout (row=quad*4+r, col d=ni*16+l16)
    f32x4 o5 = {};            // l accumulator (col 0 = row-sum of P)
    float mst[4];             // per-row running max (rows quad*4+r)
    #pragma unroll
    for (int r = 0; r < 4; ++r) mst[r] = -1.0e30f;

    // per-thread staging coords (fixed across kt)
    int keyc[2], segc[2], swzc[2];
    const unsigned short* kb_base;
    const unsigned short* vb_base;
    {
        int c0 = tid, c1 = 256 + tid;
        keyc[0] = c0 >> 3; segc[0] = c0 & 7;
        keyc[1] = c1 >> 3; segc[1] = c1 & 7;
        #pragma unroll
        for (int i = 0; i < 2; ++i) {
            int kg = keyc[i] >> 3, kl = keyc[i] & 7;
            swzc[i] = (kg ^ segc[i]) * 8 + kl;
        }
        kb_base = qkv + (size_t)b * NN * 2304 + 768 + h * 64;
        vb_base = qkv + (size_t)b * NN * 2304 + 1536 + h * 64;
    }

    // prefetch tile 0 into regs
    bf16x8 pk[2], pv[2];
    #pragma unroll
    for (int i = 0; i < 2; ++i) {
        int gk = keyc[i]; if (gk >= NN) gk = NN - 1;   // kt=0: always < NN
        pk[i] = *(const bf16x8*)(kb_base + (size_t)gk * 2304 + segc[i] * 8);
        pv[i] = *(const bf16x8*)(vb_base + (size_t)gk * 2304 + segc[i] * 8);
    }

    for (int kt = 0; kt < 10; ++kt) {
        __syncthreads();   // previous tile's Ks/Vt/Pt reads done before overwrite
        // ---- scatter prefetched K tile [key][d], V transposed+swizzled [d][key'] ----
        #pragma unroll
        for (int i = 0; i < 2; ++i) {
            *(bf16x8*)&Ks[keyc[i] * 72 + segc[i] * 8] = pk[i];
            union { bf16x8 v; unsigned short u[8]; } t; t.v = pv[i];
            #pragma unroll
            for (int e = 0; e < 8; ++e)
                Vt[(segc[i] * 8 + e) * 72 + swzc[i]] = t.u[e];
        }
        __syncthreads();

        // ---- issue next tile's loads early (consumed after next barrier) ----
        if (kt < 9) {
            #pragma unroll
            for (int i = 0; i < 2; ++i) {
                int gk = (kt + 1) * 64 + keyc[i]; if (gk >= NN) gk = NN - 1;
                pk[i] = *(const bf16x8*)(kb_base + (size_t)gk * 2304 + segc[i] * 8);
                pv[i] = *(const bf16x8*)(vb_base + (size_t)gk * 2304 + segc[i] * 8);
            }
        }

        // ---- S = Q K^T (pre-scaled): s[ni][r] = S[quad*4+r][ni*16+l16] ----
        f32x4 s[4];
        __builtin_amdgcn_s_setprio(1);
        #pragma unroll
        for (int ni = 0; ni < 4; ++ni) {
            bf16x8 b0 = *(const bf16x8*)&Ks[(ni * 16 + l16) * 72 + quad * 8];
            bf16x8 b1 = *(const bf16x8*)&Ks[(ni * 16 + l16) * 72 + 32 + quad * 8];
            f32x4 acc = {};
            acc = __builtin_amdgcn_mfma_f32_16x16x32_bf16(qf[0], b0, acc, 0, 0, 0);
            acc = __builtin_amdgcn_mfma_f32_16x16x32_bf16(qf[1], b1, acc, 0, 0, 0);
            s[ni] = acc;
        }
        __builtin_amdgcn_s_setprio(0);

        // ---- mask invalid keys (only last tile; only key 576 is valid) ----
        if (kt == 9) {
            #pragma unroll
            for (int ni = 0; ni < 4; ++ni) {
                if (ni * 16 + l16 != 0) {
                    #pragma unroll
                    for (int r = 0; r < 4; ++r) s[ni][r] = -1.0e30f;
                }
            }
        }

        // ---- row 0 only: patch_attn extraction + attn_weight factor ----
        if (qt == 0 && wv == 0 && quad == 0) {
            #pragma unroll
            for (int ni = 0; ni < 4; ++ni) {
                int gkey = kt * 64 + ni * 16 + l16;
                if (gkey >= 1 && gkey < NN) {
                    patch[(size_t)(b * HH + h) * (NN - 1) + gkey - 1] = s[ni][0];
                    float f = aw[b * (NN - 1) + gkey - 1] * 0.1f + 0.9f;
                    s[ni][0] *= f;
                }
            }
        }

        // ---- online softmax: max via intra-quad butterfly; sums via o5 MFMA ----
        float al[4];
        #pragma unroll
        for (int r = 0; r < 4; ++r) {
            float tm = fmaxf(fmaxf(s[0][r], s[1][r]), fmaxf(s[2][r], s[3][r]));
            tm = fmaxf(tm, __shfl_xor(tm, 1));
            tm = fmaxf(tm, __shfl_xor(tm, 2));
            tm = fmaxf(tm, __shfl_xor(tm, 4));
            tm = fmaxf(tm, __shfl_xor(tm, 8));
            float nm = fmaxf(mst[r], tm);
            al[r] = __expf(mst[r] - nm);   // first tile: exp(-1e30) -> 0
            mst[r] = nm;
        }
        #pragma unroll
        for (int r = 0; r < 4; ++r) {
            #pragma unroll
            for (int ni = 0; ni < 4; ++ni) {
                float p = __expf(s[ni][r] - mst[r]);   // masked: exp(-1e30) -> 0
                Pt[wv][(quad * 4 + r) * 72 + ni * 16 + l16] = f2b(p);
            }
            #pragma unroll
            for (int ni = 0; ni < 4; ++ni) o[ni][r] *= al[r];
            o5[r] *= al[r];
        }

        // ---- O += P V ; l-column += P 1 ----
        __builtin_amdgcn_s_setprio(1);
        #pragma unroll
        for (int kc = 0; kc < 2; ++kc) {
            bf16x8 af = *(const bf16x8*)&Pt[wv][l16 * 72 + kc * 32 + quad * 8];
            #pragma unroll
            for (int ni = 0; ni < 4; ++ni) {
                int d = ni * 16 + l16;
                int gs = (kc * 4 + quad) ^ (d >> 3);   // un-swizzle key group
                bf16x8 vf = *(const bf16x8*)&Vt[d * 72 + gs * 8];
                o[ni] = __builtin_amdgcn_mfma_f32_16x16x32_bf16(af, vf, o[ni], 0, 0, 0);
            }
            o5 = __builtin_amdgcn_mfma_f32_16x16x32_bf16(af, onesf.v, o5, 0, 0, 0);
        }
        __builtin_amdgcn_s_setprio(0);
    }

    // ---- finalize: l for row quad*4+r lives in lane (quad,0) col 0 of o5 ----
    #pragma unroll
    for (int r = 0; r < 4; ++r) {
        float lr = __shfl(o5[r], quad << 4);
        float inv = (lr > 0.f) ? __builtin_amdgcn_rcpf(lr) : 0.f;
        int row = qt * 64 + wv * 16 + quad * 4 + r;
        if (row < NN) {
            #pragma unroll
            for (int ni = 0; ni < 4; ++ni)
                O[(size_t)(b * NN + row) * CC + h * 64 + ni * 16 + l16] = f2b(o[ni][r] * inv);
        }
    }
}

// ---------------------------------------------------------------------------
extern "C" void kernel_launch(void* const* d_in, const int* in_sizes, int n_in,
                              void* d_out, int out_size, void* d_ws, size_t ws_size,
                              hipStream_t stream) {
    const float* x       = (const float*)d_in[0];
    const float* aw      = (const float*)d_in[1];
    const float* ln1w    = (const float*)d_in[2];
    const float* ln1b    = (const float*)d_in[3];
    const float* qkvw_f  = (const float*)d_in[4];
    const float* qkvb    = (const float*)d_in[5];
    const float* projw_f = (const float*)d_in[6];
    const float* projb   = (const float*)d_in[7];
    const float* ln2w    = (const float*)d_in[8];
    const float* ln2b    = (const float*)d_in[9];
    const float* fc1w_f  = (const float*)d_in[10];
    const float* fc1b    = (const float*)d_in[11];
    const float* fc2w_f  = (const float*)d_in[12];
    const float* fc2b    = (const float*)d_in[13];

    // workspace layout (g1 aliases h_bf+qkv, both dead before FC1). ~240 MB.
    char* ws = (char*)d_ws;
    unsigned short* h_bf  = (unsigned short*)(ws + 0);            // 18464x768 bf16
    unsigned short* qkv   = (unsigned short*)(ws + 28360704);     // 18464x2304 bf16
    unsigned short* g1    = (unsigned short*)(ws + 0);            // 18464x3072 bf16 (alias)
    unsigned short* attno = (unsigned short*)(ws + 113442816);    // 18464x768 bf16
    float*          x1    = (float*)(ws + 141803520);             // 18464x768 f32
    unsigned short* h2    = (unsigned short*)(ws + 198524928);    // 18464x768 bf16
    unsigned short* qkvw  = (unsigned short*)(ws + 226885632);    // 2304x768 bf16
    unsigned short* projw = (unsigned short*)(ws + 230424576);    // 768x768 bf16
    unsigned short* fc1w  = (unsigned short*)(ws + 231604224);    // 3072x768 bf16
    unsigned short* fc2w  = (unsigned short*)(ws + 236322816);    // 768x3072 bf16

    float* out_x = (float*)d_out;
    float* out_patch = out_x + (size_t)MROWS * CC;

    // 152 = 8 * ceil(145 m-tiles / 8) -- padded for the XCD swizzle
    cvt4<<<1024, 256, 0, stream>>>(qkvw_f, 2304 * 768, qkvw,
                                   projw_f, 768 * 768, projw,
                                   fc1w_f, 3072 * 768, fc1w,
                                   fc2w_f, 768 * 3072, fc2w);
    ln_kernel<<<MROWS / 4, 256, 0, stream>>>(x, ln1w, ln1b, h_bf);
    gemm_bt<0><<<dim3(18, 152), 256, 0, stream>>>(h_bf, qkvw, qkvb, nullptr, qkv, nullptr,
                                                  MROWS, 2304, 768);
    attn_mfma<<<dim3(10, HH, BB), 256, 0, stream>>>(qkv, aw, attno, out_patch);
    gemm_bt<2><<<dim3(6, 152), 256, 0, stream>>>(attno, projw, projb, x, nullptr, x1,
                                                 MROWS, 768, 768);
    ln_kernel<<<MROWS / 4, 256, 0, stream>>>(x1, ln2w, ln2b, h2);
    gemm_bt<1><<<dim3(24, 152), 256, 0, stream>>>(h2, fc1w, fc1b, nullptr, g1, nullptr,
                                                  MROWS, 3072, 768);
    gemm_bt<2><<<dim3(6, 152), 256, 0, stream>>>(g1, fc2w, fc2b, x1, nullptr, out_x,
                                                 MROWS, 768, 3072);
}